// Round 1
// baseline (196.334 us; speedup 1.0000x reference)
//
#include <hip/hip_runtime.h>

namespace {

constexpr float FF[12] = {0.0144f, 0.0272f, 0.0526f, 0.0972f, 0.193f, 0.63f,
                          -0.63f, -0.193f, -0.0972f, -0.0526f, -0.0272f, -0.0144f};
constexpr float SQ2   = 1.41421356237309515f;
constexpr float NISQ2 = -0.70710678118654752f;

// Horizontal 12-tap correlation on one LDS row (float4-grouped), periodic width W4*4.
// out[m] = sum_a FF[a] * row[(j4*4 + m + a - O) mod (W4*4)],  O in {5,6}.
// Window loads: 5 aligned float4 groups covering logical cols [j4*4-8, j4*4+12).
template <int O, int W4>
__device__ __forceinline__ float4 hconv(const float4* R4, int row4, int j4) {
  float r[20];
#pragma unroll
  for (int d = 0; d < 5; ++d) {
    float4 t = R4[row4 + ((j4 + d - 2) & (W4 - 1))];
    r[4 * d + 0] = t.x; r[4 * d + 1] = t.y; r[4 * d + 2] = t.z; r[4 * d + 3] = t.w;
  }
  float4 o = make_float4(0.f, 0.f, 0.f, 0.f);
#pragma unroll
  for (int a = 0; a < 12; ++a) {
    const float fa = FF[a];
    o.x += fa * r[8 + 0 + a - O];
    o.y += fa * r[8 + 1 + a - O];
    o.z += fa * r[8 + 2 + a - O];
    o.w += fa * r[8 + 3 + a - O];
  }
  return o;
}

// Vertical 12-tap correlation, plain periodic rows (stage 1: 128 rows x 32 groups).
template <int O>
__device__ __forceinline__ float4 vconv_s1(const float4* S4, int i, int j4) {
  float4 o = make_float4(0.f, 0.f, 0.f, 0.f);
#pragma unroll
  for (int a = 0; a < 12; ++a) {
    const float fa = FF[a];
    float4 v = S4[((i + a - O) & 127) * 32 + j4];
    o.x += fa * v.x; o.y += fa * v.y; o.z += fa * v.z; o.w += fa * v.w;
  }
  return o;
}

// Vertical 12-tap correlation, qper_col rows (stage 2: 128 rows x 64 groups;
// out-of-range rows wrap with column+128 shift == group XOR 32).
template <int O>
__device__ __forceinline__ float4 vconv_s2(const float4* S4, int i, int j4) {
  float4 o = make_float4(0.f, 0.f, 0.f, 0.f);
#pragma unroll
  for (int a = 0; a < 12; ++a) {
    const float fa = FF[a];
    int r = i + a - O;
    int idx = ((unsigned)r < 128u) ? (r * 64 + j4) : ((r & 127) * 64 + (j4 ^ 32));
    float4 v = S4[idx];
    o.x += fa * v.x; o.y += fa * v.y; o.z += fa * v.z; o.w += fa * v.w;
  }
  return o;
}

}  // namespace

// ---------------- Stage 1: fbrec(Y0, Y1, '2c', 'per') -> x (8,64,128,256) ----------------
// One block per (b, cc) plane; cc<32: Y0=y1[b,cc], Y1=y0[b,cc]; else Y0=y2, Y1=y3.
__global__ __launch_bounds__(1024) void s1_kernel(
    const float* __restrict__ y0, const float* __restrict__ y1,
    const float* __restrict__ y2, const float* __restrict__ y3,
    float* __restrict__ xout) {
  __shared__ float bufA[16384];  // 128x128
  __shared__ float bufB[16384];
  float4* A4 = reinterpret_cast<float4*>(bufA);
  float4* B4 = reinterpret_cast<float4*>(bufB);

  const int p  = blockIdx.x;   // 0..511
  const int b  = p >> 6;
  const int cc = p & 63;
  const int sub = (b * 32 + (cc & 31)) << 14;  // plane offset into 32-channel inputs
  const float* Y0 = (cc < 32 ? y1 : y2) + sub;
  const float* Y1 = (cc < 32 ? y0 : y3) + sub;
  const float4* Y04 = reinterpret_cast<const float4*>(Y0);
  const float4* Y14 = reinterpret_cast<const float4*>(Y1);
  float* xp = xout + (size_t)p * 32768;

  const int tid = threadIdx.x;

  // 1. load Y0 plane -> bufA
#pragma unroll
  for (int k = 0; k < 4; ++k) A4[tid + k * 1024] = Y04[tid + k * 1024];
  __syncthreads();

  // 2. bufB = vert conv offset-5 of Y0
#pragma unroll
  for (int k = 0; k < 4; ++k) {
    int g = tid + k * 1024;
    B4[g] = vconv_s1<5>(A4, g >> 5, g & 31);
  }
  __syncthreads();

  // 3. bufA = p1 = -1/sqrt2 * (Y1 + horz conv offset-5 of bufB)
#pragma unroll
  for (int k = 0; k < 4; ++k) {
    int g = tid + k * 1024;
    int i = g >> 5, j4 = g & 31;
    float4 h = hconv<5, 32>(B4, i * 32, j4);
    float4 yv = Y14[g];
    float4 o;
    o.x = NISQ2 * (yv.x + h.x);
    o.y = NISQ2 * (yv.y + h.y);
    o.z = NISQ2 * (yv.z + h.z);
    o.w = NISQ2 * (yv.w + h.w);
    A4[g] = o;
  }
  __syncthreads();

  // 4. bufB = vert conv offset-6 of p1
#pragma unroll
  for (int k = 0; k < 4; ++k) {
    int g = tid + k * 1024;
    B4[g] = vconv_s1<6>(A4, g >> 5, g & 31);
  }
  __syncthreads();

  // 5. bufB = p0 = sqrt2*Y0 + horz conv offset-6 of bufB  (register-staged, Y0 reloaded from L2)
  float4 pv[4];
#pragma unroll
  for (int k = 0; k < 4; ++k) {
    int g = tid + k * 1024;
    int i = g >> 5, j4 = g & 31;
    float4 h = hconv<6, 32>(B4, i * 32, j4);
    float4 yv = Y04[g];
    pv[k].x = SQ2 * yv.x + h.x;
    pv[k].y = SQ2 * yv.y + h.y;
    pv[k].z = SQ2 * yv.z + h.z;
    pv[k].w = SQ2 * yv.w + h.w;
  }
  __syncthreads();
#pragma unroll
  for (int k = 0; k < 4; ++k) B4[tid + k * 1024] = pv[k];
  __syncthreads();

  // 6. qprec '2c' permute: x[i,jo], J=(i+jo)&255; even J -> p0[(i-J/2)&127, J/2] (bufB),
  //    odd J -> p1[(i-1-J/2)&127, J/2] (bufA).  Per float4 group, J parity is uniform per m.
#pragma unroll
  for (int k = 0; k < 8; ++k) {
    int t = tid + k * 1024;        // 8192 float4 groups of the 128x256 output plane
    int i = t >> 6;
    int j4b = (t & 63) << 2;
    float tmp[4];
#pragma unroll
    for (int m = 0; m < 4; ++m) {
      int jo = j4b + m;
      int J = (i + jo) & 255;
      int c = J >> 1;
      float v;
      if (J & 1) {
        int r = (i - 1 - c) & 127;
        v = bufA[r * 128 + c];
      } else {
        int r = (i - c) & 127;
        v = bufB[r * 128 + c];
      }
      tmp[m] = v;
    }
    reinterpret_cast<float4*>(xp)[t] = make_float4(tmp[0], tmp[1], tmp[2], tmp[3]);
  }
}

// ---------------- Stage 2: fbrec(x0, x1, '1r', 'qper_col') -> out (8,32,256,256) -----------
// One block per (b, c) plane; x0 = x[:, c], x1 = x[:, 32+c] of the (8,64,128,256) buffer.
__global__ __launch_bounds__(1024) void s2_kernel(const float* __restrict__ x,
                                                  float* __restrict__ out) {
  __shared__ float buf[32768];  // 128x256
  float4* X4 = reinterpret_cast<float4*>(buf);

  const int q = blockIdx.x;  // 0..255
  const int b = q >> 5, c = q & 31;
  const float* x0 = x + (size_t)(b * 64 + c) * 32768;
  const float* x1 = x + (size_t)(b * 64 + 32 + c) * 32768;
  const float4* x04 = reinterpret_cast<const float4*>(x0);
  const float4* x14 = reinterpret_cast<const float4*>(x1);
  float* op = out + (size_t)q * 65536;

  const int tid = threadIdx.x;
  float4 tv[8];

  // 1. load x0 plane
#pragma unroll
  for (int k = 0; k < 8; ++k) X4[tid + k * 1024] = x04[tid + k * 1024];
  __syncthreads();

  // 2. buf = vert conv offset-5 (qper rows), register-staged (in-place)
#pragma unroll
  for (int k = 0; k < 8; ++k) {
    int g = tid + k * 1024;
    tv[k] = vconv_s2<5>(X4, g >> 6, g & 63);
  }
  __syncthreads();
#pragma unroll
  for (int k = 0; k < 8; ++k) X4[tid + k * 1024] = tv[k];
  __syncthreads();

  // 3. buf = p1 = -1/sqrt2 * (x1 + horz conv offset-5)
#pragma unroll
  for (int k = 0; k < 8; ++k) {
    int g = tid + k * 1024;
    int i = g >> 6, j4 = g & 63;
    float4 h = hconv<5, 64>(X4, i * 64, j4);
    float4 xv = x14[g];
    tv[k].x = NISQ2 * (xv.x + h.x);
    tv[k].y = NISQ2 * (xv.y + h.y);
    tv[k].z = NISQ2 * (xv.z + h.z);
    tv[k].w = NISQ2 * (xv.w + h.w);
  }
  __syncthreads();
#pragma unroll
  for (int k = 0; k < 8; ++k) X4[tid + k * 1024] = tv[k];
  __syncthreads();

  // 3b. odd-I outputs while buf == p1:  out[i,jo] = p1[r, (jo-1-r)&255], I=(i+jo)&255 odd, r=I>>1
#pragma unroll
  for (int k = 0; k < 32; ++k) {
    int t = tid + k * 1024;       // 32768 odd positions
    int i = t >> 7;
    int u = t & 127;
    int jo = (u << 1) | ((i + 1) & 1);
    int r = ((i + jo) & 255) >> 1;
    int cc2 = (jo - 1 - r) & 255;
    op[i * 256 + jo] = buf[r * 256 + cc2];
  }
  // (reads only; the sync after step-4 compute orders these vs. the next buf overwrite)

  // 4. buf = vert conv offset-6 of p1 (qper rows)
#pragma unroll
  for (int k = 0; k < 8; ++k) {
    int g = tid + k * 1024;
    tv[k] = vconv_s2<6>(X4, g >> 6, g & 63);
  }
  __syncthreads();
#pragma unroll
  for (int k = 0; k < 8; ++k) X4[tid + k * 1024] = tv[k];
  __syncthreads();

  // 5. buf = p0 = sqrt2*x0 + horz conv offset-6
#pragma unroll
  for (int k = 0; k < 8; ++k) {
    int g = tid + k * 1024;
    int i = g >> 6, j4 = g & 63;
    float4 h = hconv<6, 64>(X4, i * 64, j4);
    float4 xv = x04[g];
    tv[k].x = SQ2 * xv.x + h.x;
    tv[k].y = SQ2 * xv.y + h.y;
    tv[k].z = SQ2 * xv.z + h.z;
    tv[k].w = SQ2 * xv.w + h.w;
  }
  __syncthreads();
#pragma unroll
  for (int k = 0; k < 8; ++k) X4[tid + k * 1024] = tv[k];
  __syncthreads();

  // 6. even-I outputs: out[i,jo] = p0[r, (jo-r)&255], I even, r=I>>1
#pragma unroll
  for (int k = 0; k < 32; ++k) {
    int t = tid + k * 1024;
    int i = t >> 7;
    int u = t & 127;
    int jo = (u << 1) | (i & 1);
    int r = ((i + jo) & 255) >> 1;
    int cc2 = (jo - r) & 255;
    op[i * 256 + jo] = buf[r * 256 + cc2];
  }
}

extern "C" void kernel_launch(void* const* d_in, const int* in_sizes, int n_in,
                              void* d_out, int out_size, void* d_ws, size_t ws_size,
                              hipStream_t stream) {
  const float* y0 = (const float*)d_in[0];
  const float* y1 = (const float*)d_in[1];
  const float* y2 = (const float*)d_in[2];
  const float* y3 = (const float*)d_in[3];
  float* xws = (float*)d_ws;           // (8,64,128,256) fp32 = 64 MiB intermediate
  float* outp = (float*)d_out;         // (8,32,256,256) fp32

  s1_kernel<<<512, 1024, 0, stream>>>(y0, y1, y2, y3, xws);
  s2_kernel<<<256, 1024, 0, stream>>>(xws, outp);
}